// Round 11
// baseline (1742.619 us; speedup 1.0000x reference)
//
#include <hip/hip_runtime.h>

// GRU: B=64, T=512, IN=256, H=1024, OUT=10.
// Persistent kernel, 256 blocks = 32 j-slices x 8 batch-groups (r9-proven).
// Sync = data-as-flag, agent scope (sc1) ONLY: h elements are u32
// {epoch:16|fp16:16}, published as 8B pairs (single-copy atomic; lo-epoch
// certifies the u64 -- r8-proven). sc0 written off (r4/r10 hangs).
// This round: 2-deep pipelined poll -- two full snapshot buffers d/e in
// flight, alternating reissue, halving discovery granularity (~L/2 vs L).
// Compiler-managed counted waitcnts (no inline asm); leftover in-flight set
// drained by the existing __syncthreads.

#define TT  512
#define BB  64
#define KIN 256
#define HH  1024

typedef _Float16 half8   __attribute__((ext_vector_type(8)));
typedef _Float16 half4v  __attribute__((ext_vector_type(4)));
typedef float    float4v __attribute__((ext_vector_type(4)));

// ---- workspace layout (bytes) ----
#define XF_OFF   0u           // fp16 x [T][B][K] = 16,777,216
#define HB0_OFF  16777216u    // u32 {tag|h} ping [B][H] = 262,144
#define HB1_OFF  17039360u    // u32 {tag|h} pong [B][H] = 262,144

// x[b][t][k] f32 -> xf[t][b][k] fp16
__global__ __launch_bounds__(256) void k_prep_x(const float* __restrict__ x,
                                                _Float16* __restrict__ xf) {
    const int t   = blockIdx.x;
    const int tid = threadIdx.x;
    const int k4  = (tid & 63) << 2;
    const int bw  = tid >> 6;
#pragma unroll
    for (int bi = 0; bi < 16; ++bi) {
        const int b = (bw << 4) + bi;
        float4v v = *(const float4v*)(x + ((size_t)b * TT + t) * KIN + k4);
        half4v h;
        h[0] = (_Float16)v[0]; h[1] = (_Float16)v[1];
        h[2] = (_Float16)v[2]; h[3] = (_Float16)v[3];
        *(half4v*)(xf + ((size_t)t * BB + b) * KIN + k4) = h;
    }
}

__device__ __forceinline__ unsigned long long ld_ag64(const void* p) {
    return __hip_atomic_load((const unsigned long long*)p, __ATOMIC_RELAXED,
                             __HIP_MEMORY_SCOPE_AGENT);
}
__device__ __forceinline__ void st_ag64(void* p, unsigned long long v) {
    __hip_atomic_store((unsigned long long*)p, v, __ATOMIC_RELAXED,
                       __HIP_MEMORY_SCOPE_AGENT);
}

__device__ __forceinline__ float sigm_fast(float z) {
    return __builtin_amdgcn_rcpf(1.f + __expf(-z));
}
__device__ __forceinline__ float tanh_fast(float z) {
    float e = __expf(-2.f * __builtin_fabsf(z));
    float r = (1.f - e) * __builtin_amdgcn_rcpf(1.f + e);
    return __builtin_copysignf(r, z);
}

__global__ __launch_bounds__(256, 1) void k_gru_persist(
    const _Float16* __restrict__ xf, const float* __restrict__ Wx,
    const float* __restrict__ bx, const float* __restrict__ Wh,
    const float* __restrict__ bh, const float* __restrict__ Wfc,
    const float* __restrict__ bfc, unsigned* __restrict__ hb0,
    unsigned* __restrict__ hb1, float* __restrict__ out)
{
    __shared__ char smem[36864];
    _Float16* h_lds = (_Float16*)smem;             // [8 b][1024 k] swz, 16KB
    float*    red   = (float*)(smem + 16384);      // 2 jt x [(c*4+w)*8+b][20]

    const int tid  = threadIdx.x;
    const int lane = tid & 63;
    const int wv   = tid >> 6;          // wave = K-slice (256 k each)
    const int jsl  = blockIdx.x & 31;   // j-slice (32 of them)
    const int btl  = blockIdx.x >> 5;   // batch group (8 of them, 8 b each)
    const int j0   = jsl << 5;          // 32 j per block
    const int b0   = btl << 3;          // 8 b per block

    const int arow = lane & 15;         // MFMA A row (j) / B+D col (b)
    const int kg   = lane >> 4;         // MFMA k-group
    const int br8  = arow & 7;          // clamped b row (8 valid batches)
    const int swz  = br8 << 4;

    // ---- resident weights: single fp16 MFMA A-fragments, 2 j-tiles ----
    half8 ah[2][3][8], ax[2][3][2];
#pragma unroll
    for (int jt = 0; jt < 2; ++jt) {
#pragma unroll
        for (int g = 0; g < 3; ++g) {
            const int row = (g << 10) + j0 + (jt << 4) + arow;
#pragma unroll
            for (int s = 0; s < 8; ++s) {
                const float* p = Wh + (size_t)row * HH + (wv << 8) + (s << 5) + (kg << 3);
#pragma unroll
                for (int e = 0; e < 8; ++e) ah[jt][g][s][e] = (_Float16)p[e];
            }
#pragma unroll
            for (int s = 0; s < 2; ++s) {
                const float* p = Wx + (size_t)row * KIN + (wv << 6) + (s << 5) + (kg << 3);
#pragma unroll
                for (int e = 0; e < 8; ++e) ax[jt][g][s][e] = (_Float16)p[e];
            }
        }
    }

    const int jh  = tid & 31;       // owned j (consecutive tid -> consecutive j)
    const int bhi = tid >> 5;       // owned b (0..7)
    const int j   = j0 + jh;
    const int jt_f = jh >> 4, jrow_f = jh & 15;
    const float bxr = bx[j], bxi = bx[HH + j], bxn = bx[2 * HH + j];
    const float bhr = bh[j], bhii = bh[HH + j], bhn = bh[2 * HH + j];
    float hprev = 0.f;

    // ---- x B-fragments in registers ----
    const size_t xoff = (size_t)(b0 + br8) * KIN + (wv << 6) + (kg << 3);
    half8 xb0 = *(const half8*)(xf + xoff);
    half8 xb1 = *(const half8*)(xf + xoff + 32);

    for (int t = 0; t < TT; ++t) {
        const unsigned* hs = (t & 1) ? hb1 : hb0;
        unsigned*       hd = (t & 1) ? hb0 : hb1;
        const unsigned  tgt = (unsigned)t;

        // snapshot issue / check / strip helpers (static array identity ->
        // no runtime indexing, rule-#20 safe)
        auto issue = [&](unsigned long long (&buf)[16]) {
#pragma unroll
            for (int i = 0; i < 16; ++i) {
                int c = tid + (i << 8);
                buf[i] = ld_ag64(hs + ((size_t)(b0 + (c >> 9)) << 10)
                                    + ((c & 511) << 1));
            }
        };
        auto check = [&](const unsigned long long (&buf)[16]) -> bool {
            unsigned mn = 0xffffu;
#pragma unroll
            for (int i = 0; i < 16; ++i) {
                unsigned ep = (unsigned)(buf[i] >> 16) & 0xffffu;
                mn = (ep < mn) ? ep : mn;
            }
            return mn >= tgt;
        };
        auto strip = [&](const unsigned long long (&buf)[16]) {
#pragma unroll
            for (int i = 0; i < 16; ++i) {
                int c = tid + (i << 8);
                int br = c >> 9, pc = c & 511;
                unsigned lo = (unsigned)buf[i];
                unsigned hi = (unsigned)(buf[i] >> 32);
                *(unsigned*)((char*)h_lds + (br << 11)
                    + ((pc << 2) ^ ((br & 7) << 4))) = (lo & 0xffffu) | (hi << 16);
            }
        };

        // ---- (A) 2-deep pipelined snapshot issue ----
        unsigned long long d[16], e[16];
        issue(d);
        issue(e);

        // ---- (C) prefetch next-step x fragments (overlaps poll) ----
        const int tn = (t + 1 < TT) ? (t + 1) : t;
        const size_t xoffn = (size_t)tn * (BB * KIN) + xoff;
        half8 nb0 = *(const half8*)(xf + xoffn);
        half8 nb1 = *(const half8*)(xf + xoffn + 32);

        // ---- (B) x-MFMAs (no h dependency; overlap producer latency) ----
        float4v ar0 = {0,0,0,0}, ai0 = {0,0,0,0}, ax0 = {0,0,0,0}, ah0 = {0,0,0,0};
        float4v ar1 = {0,0,0,0}, ai1 = {0,0,0,0}, ax1 = {0,0,0,0}, ah1 = {0,0,0,0};
        ar0 = __builtin_amdgcn_mfma_f32_16x16x32_f16(ax[0][0][0], xb0, ar0, 0, 0, 0);
        ai0 = __builtin_amdgcn_mfma_f32_16x16x32_f16(ax[0][1][0], xb0, ai0, 0, 0, 0);
        ax0 = __builtin_amdgcn_mfma_f32_16x16x32_f16(ax[0][2][0], xb0, ax0, 0, 0, 0);
        ar1 = __builtin_amdgcn_mfma_f32_16x16x32_f16(ax[1][0][0], xb0, ar1, 0, 0, 0);
        ai1 = __builtin_amdgcn_mfma_f32_16x16x32_f16(ax[1][1][0], xb0, ai1, 0, 0, 0);
        ax1 = __builtin_amdgcn_mfma_f32_16x16x32_f16(ax[1][2][0], xb0, ax1, 0, 0, 0);
        ar0 = __builtin_amdgcn_mfma_f32_16x16x32_f16(ax[0][0][1], xb1, ar0, 0, 0, 0);
        ai0 = __builtin_amdgcn_mfma_f32_16x16x32_f16(ax[0][1][1], xb1, ai0, 0, 0, 0);
        ax0 = __builtin_amdgcn_mfma_f32_16x16x32_f16(ax[0][2][1], xb1, ax0, 0, 0, 0);
        ar1 = __builtin_amdgcn_mfma_f32_16x16x32_f16(ax[1][0][1], xb1, ar1, 0, 0, 0);
        ai1 = __builtin_amdgcn_mfma_f32_16x16x32_f16(ax[1][1][1], xb1, ai1, 0, 0, 0);
        ax1 = __builtin_amdgcn_mfma_f32_16x16x32_f16(ax[1][2][1], xb1, ax1, 0, 0, 0);

        // ---- (D) alternating poll: check d / reissue d / check e / ... ----
        // Per-lane divergent exit; certified buffer is a complete snapshot
        // (every u64 lo-epoch >= t; 8B pair store single-copy atomic).
        bool useD;
        for (;;) {
            if (check(d)) { useD = true;  break; }
            issue(d);
            if (check(e)) { useD = false; break; }
            issue(e);
        }

        // ---- (E) strip certified snapshot -> swizzled LDS ----
        if (useD) strip(d); else strip(e);
        __syncthreads();   // implicit vmcnt(0): drains leftover in-flight set

        // ---- (F) h-MFMAs: each bf feeds 6 MFMAs (3 gates x 2 j-tiles) ----
#pragma unroll
        for (int s = 0; s < 8; ++s) {
            half8 bf = *(const half8*)((char*)h_lds + (br8 << 11)
                        + (((wv << 9) + (s << 6) + (kg << 4)) ^ swz));
            ar0 = __builtin_amdgcn_mfma_f32_16x16x32_f16(ah[0][0][s], bf, ar0, 0, 0, 0);
            ai0 = __builtin_amdgcn_mfma_f32_16x16x32_f16(ah[0][1][s], bf, ai0, 0, 0, 0);
            ah0 = __builtin_amdgcn_mfma_f32_16x16x32_f16(ah[0][2][s], bf, ah0, 0, 0, 0);
            ar1 = __builtin_amdgcn_mfma_f32_16x16x32_f16(ah[1][0][s], bf, ar1, 0, 0, 0);
            ai1 = __builtin_amdgcn_mfma_f32_16x16x32_f16(ah[1][1][s], bf, ai1, 0, 0, 0);
            ah1 = __builtin_amdgcn_mfma_f32_16x16x32_f16(ah[1][2][s], bf, ah1, 0, 0, 0);
        }

        // ---- (G) cross-wave K reduction (conflict-free layout) ----
        if (arow < 8) {
            int wb = ((wv << 3) + arow) * 20 + (kg << 2);
            *(float4v*)&red[wb]              = ar0;
            *(float4v*)&red[wb + 640]        = ai0;
            *(float4v*)&red[wb + 1280]       = ax0;
            *(float4v*)&red[wb + 1920]       = ah0;
            *(float4v*)&red[wb + 2560]       = ar1;
            *(float4v*)&red[wb + 2560+640]   = ai1;
            *(float4v*)&red[wb + 2560+1280]  = ax1;
            *(float4v*)&red[wb + 2560+1920]  = ah1;
        }
        __syncthreads();

        float sr = 0.f, si = 0.f, sx = 0.f, sh = 0.f;
        {
            const int base = jt_f * 2560 + jrow_f;
#pragma unroll
            for (int w2 = 0; w2 < 4; ++w2) {
                int rb = base + ((w2 << 3) + bhi) * 20;
                sr += red[rb];
                si += red[rb + 640];
                sx += red[rb + 1280];
                sh += red[rb + 1920];
            }
        }
        float rg = sigm_fast(sr + bxr + bhr);
        float ig = sigm_fast(si + bxi + bhii);
        float ng = tanh_fast(sx + bxn + rg * (sh + bhn));
        hprev = ng + ig * (hprev - ng);

        // ---- (H) publish {epoch|h} pair (jh, jh^1) as one 8B store ----
        unsigned short hb16;
        { union { _Float16 f; unsigned short u; } cv; cv.f = (_Float16)hprev; hb16 = cv.u; }
        unsigned myw = (((unsigned)(t + 1)) << 16) | (unsigned)hb16;
        unsigned other = (unsigned)__shfl_xor((int)myw, 1, 64);
        if ((jh & 1) == 0) {
            unsigned long long pv = (unsigned long long)myw
                                  | ((unsigned long long)other << 32);
            st_ag64(hd + ((size_t)(b0 + bhi) << 10) + j, pv);
        }

        xb0 = nb0; xb1 = nb1;
        // no barrier: epochs carry the synchronization
    }

    // ---- FC: blocks 0..63 compute out[b][:] from final h (hb0, epoch 512) ----
    if (blockIdx.x < 64) {
        __syncthreads();
        const int b = blockIdx.x;
        const unsigned ftgt = (unsigned)TT;
        unsigned long long e0, e1;
        do { e0 = ld_ag64(hb0 + ((size_t)b << 10) + (tid << 2)); }
        while (((unsigned)(e0 >> 16) & 0xffffu) < ftgt || (unsigned)(e0 >> 48) < ftgt);
        do { e1 = ld_ag64(hb0 + ((size_t)b << 10) + (tid << 2) + 2); }
        while (((unsigned)(e1 >> 16) & 0xffffu) < ftgt || (unsigned)(e1 >> 48) < ftgt);

        float hv[4];
        { union { unsigned short u; _Float16 f; } cv;
          cv.u = (unsigned short)(e0 & 0xffffu);         hv[0] = (float)cv.f;
          cv.u = (unsigned short)((e0 >> 32) & 0xffffu); hv[1] = (float)cv.f;
          cv.u = (unsigned short)(e1 & 0xffffu);         hv[2] = (float)cv.f;
          cv.u = (unsigned short)((e1 >> 32) & 0xffffu); hv[3] = (float)cv.f; }

        float partial[10];
#pragma unroll
        for (int o = 0; o < 10; ++o) {
            float4v w4 = *(const float4v*)(Wfc + (size_t)o * HH + (tid << 2));
            partial[o] = hv[0]*w4[0] + hv[1]*w4[1] + hv[2]*w4[2] + hv[3]*w4[3];
        }
        float* r = (float*)smem;   // [10][256]
#pragma unroll
        for (int o = 0; o < 10; ++o) r[o * 256 + tid] = partial[o];
        __syncthreads();
        for (int off = 128; off >= 1; off >>= 1) {
            if (tid < off) {
#pragma unroll
                for (int o = 0; o < 10; ++o)
                    r[o * 256 + tid] += r[o * 256 + tid + off];
            }
            __syncthreads();
        }
        if (tid < 10) out[b * 10 + tid] = r[tid * 256] + bfc[tid];
    }
}

extern "C" void kernel_launch(void* const* d_in, const int* in_sizes, int n_in,
                              void* d_out, int out_size, void* d_ws, size_t ws_size,
                              hipStream_t stream) {
    (void)in_sizes; (void)n_in; (void)out_size; (void)ws_size;
    const float* x   = (const float*)d_in[0];
    const float* Wx  = (const float*)d_in[1];
    const float* bx  = (const float*)d_in[2];
    const float* Wh  = (const float*)d_in[3];
    const float* bh  = (const float*)d_in[4];
    const float* Wfc = (const float*)d_in[5];
    const float* bfc = (const float*)d_in[6];
    float* out = (float*)d_out;

    char* ws = (char*)d_ws;
    _Float16* xf  = (_Float16*)(ws + XF_OFF);
    unsigned* hb0 = (unsigned*)(ws + HB0_OFF);
    unsigned* hb1 = (unsigned*)(ws + HB1_OFF);

    // reset BOTH packed h buffers every call (epochs must restart at 0;
    // harness replays without re-poisoning)
    hipMemsetAsync(ws + HB0_OFF, 0, 524288, stream);

    k_prep_x<<<512, 256, 0, stream>>>(x, xf);
    k_gru_persist<<<256, 256, 0, stream>>>(xf, Wx, bx, Wh, bh, Wfc, bfc,
                                           hb0, hb1, out);
}

// Round 14
// 1632.039 us; speedup vs baseline: 1.0678x; 1.0678x over previous
//
#include <hip/hip_runtime.h>

// GRU: B=64, T=512, IN=256, H=1024, OUT=10.
// SESSION-BEST (r9 reproduction): persistent kernel, 256 blocks =
// 32 j-slices x 8 batch-groups. Sync = data-as-flag: each h element is a
// u32 {epoch:16 | fp16:16}; producers publish 8B pairs (single-copy atomic,
// lo-epoch certifies the u64); consumers pend-mask poll (reload only stale
// chunks) then strip-once to swizzled LDS. Weights resident as single-fp16
// MFMA A-fragments (220 VGPR). NOTE: 8B store / 8B load size-matching is
// load-bearing -- 4B-store variants (r6/r12/r13) silently corrupt; agent
// (sc1) scope is the only validated cross-CU channel (sc0 hangs: r4/r10).

#define TT  512
#define BB  64
#define KIN 256
#define HH  1024

typedef _Float16 half8   __attribute__((ext_vector_type(8)));
typedef _Float16 half4v  __attribute__((ext_vector_type(4)));
typedef float    float4v __attribute__((ext_vector_type(4)));

// ---- workspace layout (bytes) ----
#define XF_OFF   0u           // fp16 x [T][B][K] = 16,777,216
#define HB0_OFF  16777216u    // u32 {tag|h} ping [B][H] = 262,144
#define HB1_OFF  17039360u    // u32 {tag|h} pong [B][H] = 262,144

// x[b][t][k] f32 -> xf[t][b][k] fp16
__global__ __launch_bounds__(256) void k_prep_x(const float* __restrict__ x,
                                                _Float16* __restrict__ xf) {
    const int t   = blockIdx.x;
    const int tid = threadIdx.x;
    const int k4  = (tid & 63) << 2;
    const int bw  = tid >> 6;
#pragma unroll
    for (int bi = 0; bi < 16; ++bi) {
        const int b = (bw << 4) + bi;
        float4v v = *(const float4v*)(x + ((size_t)b * TT + t) * KIN + k4);
        half4v h;
        h[0] = (_Float16)v[0]; h[1] = (_Float16)v[1];
        h[2] = (_Float16)v[2]; h[3] = (_Float16)v[3];
        *(half4v*)(xf + ((size_t)t * BB + b) * KIN + k4) = h;
    }
}

__device__ __forceinline__ unsigned long long ld_ag64(const void* p) {
    return __hip_atomic_load((const unsigned long long*)p, __ATOMIC_RELAXED,
                             __HIP_MEMORY_SCOPE_AGENT);
}
__device__ __forceinline__ void st_ag64(void* p, unsigned long long v) {
    __hip_atomic_store((unsigned long long*)p, v, __ATOMIC_RELAXED,
                       __HIP_MEMORY_SCOPE_AGENT);
}

__device__ __forceinline__ float sigm_fast(float z) {
    return __builtin_amdgcn_rcpf(1.f + __expf(-z));
}
__device__ __forceinline__ float tanh_fast(float z) {
    float e = __expf(-2.f * __builtin_fabsf(z));
    float r = (1.f - e) * __builtin_amdgcn_rcpf(1.f + e);
    return __builtin_copysignf(r, z);
}

__global__ __launch_bounds__(256, 1) void k_gru_persist(
    const _Float16* __restrict__ xf, const float* __restrict__ Wx,
    const float* __restrict__ bx, const float* __restrict__ Wh,
    const float* __restrict__ bh, const float* __restrict__ Wfc,
    const float* __restrict__ bfc, unsigned* __restrict__ hb0,
    unsigned* __restrict__ hb1, float* __restrict__ out)
{
    __shared__ char smem[36864];
    _Float16* h_lds = (_Float16*)smem;             // [8 b][1024 k] swz, 16KB
    float*    red   = (float*)(smem + 16384);      // 2 jt x [(c*4+w)*8+b][20]

    const int tid  = threadIdx.x;
    const int lane = tid & 63;
    const int wv   = tid >> 6;          // wave = K-slice (256 k each)
    const int jsl  = blockIdx.x & 31;   // j-slice (32 of them)
    const int btl  = blockIdx.x >> 5;   // batch group (8 of them, 8 b each)
    const int j0   = jsl << 5;          // 32 j per block
    const int b0   = btl << 3;          // 8 b per block

    const int arow = lane & 15;         // MFMA A row (j) / B+D col (b)
    const int kg   = lane >> 4;         // MFMA k-group
    const int br8  = arow & 7;          // clamped b row (8 valid batches)
    const int swz  = br8 << 4;

    // ---- resident weights: single fp16 MFMA A-fragments, 2 j-tiles ----
    half8 ah[2][3][8], ax[2][3][2];
#pragma unroll
    for (int jt = 0; jt < 2; ++jt) {
#pragma unroll
        for (int g = 0; g < 3; ++g) {
            const int row = (g << 10) + j0 + (jt << 4) + arow;
#pragma unroll
            for (int s = 0; s < 8; ++s) {
                const float* p = Wh + (size_t)row * HH + (wv << 8) + (s << 5) + (kg << 3);
#pragma unroll
                for (int e = 0; e < 8; ++e) ah[jt][g][s][e] = (_Float16)p[e];
            }
#pragma unroll
            for (int s = 0; s < 2; ++s) {
                const float* p = Wx + (size_t)row * KIN + (wv << 6) + (s << 5) + (kg << 3);
#pragma unroll
                for (int e = 0; e < 8; ++e) ax[jt][g][s][e] = (_Float16)p[e];
            }
        }
    }

    const int jh  = tid & 31;       // owned j (consecutive tid -> consecutive j)
    const int bhi = tid >> 5;       // owned b (0..7)
    const int j   = j0 + jh;
    const int jt_f = jh >> 4, jrow_f = jh & 15;
    const float bxr = bx[j], bxi = bx[HH + j], bxn = bx[2 * HH + j];
    const float bhr = bh[j], bhii = bh[HH + j], bhn = bh[2 * HH + j];
    float hprev = 0.f;

    // ---- x B-fragments in registers ----
    const size_t xoff = (size_t)(b0 + br8) * KIN + (wv << 6) + (kg << 3);
    half8 xb0 = *(const half8*)(xf + xoff);
    half8 xb1 = *(const half8*)(xf + xoff + 32);

    for (int t = 0; t < TT; ++t) {
        const unsigned* hs = (t & 1) ? hb1 : hb0;
        unsigned*       hd = (t & 1) ? hb0 : hb1;

        // ---- (A) issue all 16 h staging loads (8 rows x 512 u64 chunks) ----
        unsigned long long d[16];
#pragma unroll
        for (int i = 0; i < 16; ++i) {
            int c = tid + (i << 8);
            d[i] = ld_ag64(hs + ((size_t)(b0 + (c >> 9)) << 10) + ((c & 511) << 1));
        }

        // ---- (B) x-MFMAs (no h dependency; overlap producer latency) ----
        float4v ar0 = {0,0,0,0}, ai0 = {0,0,0,0}, ax0 = {0,0,0,0}, ah0 = {0,0,0,0};
        float4v ar1 = {0,0,0,0}, ai1 = {0,0,0,0}, ax1 = {0,0,0,0}, ah1 = {0,0,0,0};
        ar0 = __builtin_amdgcn_mfma_f32_16x16x32_f16(ax[0][0][0], xb0, ar0, 0, 0, 0);
        ai0 = __builtin_amdgcn_mfma_f32_16x16x32_f16(ax[0][1][0], xb0, ai0, 0, 0, 0);
        ax0 = __builtin_amdgcn_mfma_f32_16x16x32_f16(ax[0][2][0], xb0, ax0, 0, 0, 0);
        ar1 = __builtin_amdgcn_mfma_f32_16x16x32_f16(ax[1][0][0], xb0, ar1, 0, 0, 0);
        ai1 = __builtin_amdgcn_mfma_f32_16x16x32_f16(ax[1][1][0], xb0, ai1, 0, 0, 0);
        ax1 = __builtin_amdgcn_mfma_f32_16x16x32_f16(ax[1][2][0], xb0, ax1, 0, 0, 0);
        ar0 = __builtin_amdgcn_mfma_f32_16x16x32_f16(ax[0][0][1], xb1, ar0, 0, 0, 0);
        ai0 = __builtin_amdgcn_mfma_f32_16x16x32_f16(ax[0][1][1], xb1, ai0, 0, 0, 0);
        ax0 = __builtin_amdgcn_mfma_f32_16x16x32_f16(ax[0][2][1], xb1, ax0, 0, 0, 0);
        ar1 = __builtin_amdgcn_mfma_f32_16x16x32_f16(ax[1][0][1], xb1, ar1, 0, 0, 0);
        ai1 = __builtin_amdgcn_mfma_f32_16x16x32_f16(ax[1][1][1], xb1, ai1, 0, 0, 0);
        ax1 = __builtin_amdgcn_mfma_f32_16x16x32_f16(ax[1][2][1], xb1, ax1, 0, 0, 0);

        // ---- (C) prefetch next-step x fragments ----
        const int tn = (t + 1 < TT) ? (t + 1) : t;
        const size_t xoffn = (size_t)tn * (BB * KIN) + xoff;
        half8 nb0 = *(const half8*)(xf + xoffn);
        half8 nb1 = *(const half8*)(xf + xoffn + 32);

        // ---- (D) pend-mask poll (reload only stale chunks) ----
        // Producer pair-store is one aligned 8B instr (single-copy atomic),
        // so the LO epoch certifies the whole u64.
        {
            const unsigned tgt = (unsigned)t;
            unsigned pend = 0xffffu;
            for (;;) {
                unsigned np = 0;
#pragma unroll
                for (int i = 0; i < 16; ++i)
                    if ((pend >> i) & 1u)
                        if (((unsigned)(d[i] >> 16) & 0xffffu) < tgt) np |= (1u << i);
                if (np == 0) break;
                pend = np;
#pragma unroll
                for (int i = 0; i < 16; ++i)
                    if ((pend >> i) & 1u) {
                        int c = tid + (i << 8);
                        d[i] = ld_ag64(hs + ((size_t)(b0 + (c >> 9)) << 10)
                                          + ((c & 511) << 1));
                    }
            }
        }

        // ---- (E) strip tags -> swizzled LDS (once) ----
#pragma unroll
        for (int i = 0; i < 16; ++i) {
            int c = tid + (i << 8);
            int br = c >> 9, pc = c & 511;
            unsigned lo = (unsigned)d[i];
            unsigned hi = (unsigned)(d[i] >> 32);
            *(unsigned*)((char*)h_lds + (br << 11)
                + ((pc << 2) ^ ((br & 7) << 4))) = (lo & 0xffffu) | (hi << 16);
        }
        __syncthreads();

        // ---- (F) h-MFMAs: each bf feeds 6 MFMAs (3 gates x 2 j-tiles) ----
#pragma unroll
        for (int s = 0; s < 8; ++s) {
            half8 bf = *(const half8*)((char*)h_lds + (br8 << 11)
                        + (((wv << 9) + (s << 6) + (kg << 4)) ^ swz));
            ar0 = __builtin_amdgcn_mfma_f32_16x16x32_f16(ah[0][0][s], bf, ar0, 0, 0, 0);
            ai0 = __builtin_amdgcn_mfma_f32_16x16x32_f16(ah[0][1][s], bf, ai0, 0, 0, 0);
            ah0 = __builtin_amdgcn_mfma_f32_16x16x32_f16(ah[0][2][s], bf, ah0, 0, 0, 0);
            ar1 = __builtin_amdgcn_mfma_f32_16x16x32_f16(ah[1][0][s], bf, ar1, 0, 0, 0);
            ai1 = __builtin_amdgcn_mfma_f32_16x16x32_f16(ah[1][1][s], bf, ai1, 0, 0, 0);
            ah1 = __builtin_amdgcn_mfma_f32_16x16x32_f16(ah[1][2][s], bf, ah1, 0, 0, 0);
        }

        // ---- (G) cross-wave K reduction (8 b-rows, 2 jt regions) ----
        if (arow < 8) {
            int wb = ((wv << 3) + arow) * 20 + (kg << 2);   // (c=0,w=wv,b=arow)
            *(float4v*)&red[wb]              = ar0;   // jt0 c0
            *(float4v*)&red[wb + 640]        = ai0;   // jt0 c1 (+4*8*20)
            *(float4v*)&red[wb + 1280]       = ax0;   // jt0 c2
            *(float4v*)&red[wb + 1920]       = ah0;   // jt0 c3
            *(float4v*)&red[wb + 2560]       = ar1;   // jt1 c0
            *(float4v*)&red[wb + 2560+640]   = ai1;
            *(float4v*)&red[wb + 2560+1280]  = ax1;
            *(float4v*)&red[wb + 2560+1920]  = ah1;
        }
        __syncthreads();

        float sr = 0.f, si = 0.f, sx = 0.f, sh = 0.f;
        {
            const int base = jt_f * 2560 + jrow_f;
#pragma unroll
            for (int w2 = 0; w2 < 4; ++w2) {
                int rb = base + ((w2 << 3) + bhi) * 20;
                sr += red[rb];
                si += red[rb + 640];
                sx += red[rb + 1280];
                sh += red[rb + 1920];
            }
        }
        float rg = sigm_fast(sr + bxr + bhr);
        float ig = sigm_fast(si + bxi + bhii);
        float ng = tanh_fast(sx + bxn + rg * (sh + bhn));
        hprev = ng + ig * (hprev - ng);

        // ---- (H) publish {epoch|h} pair (jh, jh^1) as one 8B store ----
        unsigned short hb16;
        { union { _Float16 f; unsigned short u; } cv; cv.f = (_Float16)hprev; hb16 = cv.u; }
        unsigned myw = (((unsigned)(t + 1)) << 16) | (unsigned)hb16;
        unsigned other = (unsigned)__shfl_xor((int)myw, 1, 64);
        if ((jh & 1) == 0) {
            unsigned long long pv = (unsigned long long)myw
                                  | ((unsigned long long)other << 32);
            st_ag64(hd + ((size_t)(b0 + bhi) << 10) + j, pv);
        }

        xb0 = nb0; xb1 = nb1;
        // no barrier: epochs carry the synchronization
    }

    // ---- FC: blocks 0..63 compute out[b][:] from final h (hb0, epoch 512) ----
    if (blockIdx.x < 64) {
        __syncthreads();
        const int b = blockIdx.x;
        const unsigned ftgt = (unsigned)TT;
        unsigned long long e0, e1;
        do { e0 = ld_ag64(hb0 + ((size_t)b << 10) + (tid << 2)); }
        while (((unsigned)(e0 >> 16) & 0xffffu) < ftgt || (unsigned)(e0 >> 48) < ftgt);
        do { e1 = ld_ag64(hb0 + ((size_t)b << 10) + (tid << 2) + 2); }
        while (((unsigned)(e1 >> 16) & 0xffffu) < ftgt || (unsigned)(e1 >> 48) < ftgt);

        float hv[4];
        { union { unsigned short u; _Float16 f; } cv;
          cv.u = (unsigned short)(e0 & 0xffffu);         hv[0] = (float)cv.f;
          cv.u = (unsigned short)((e0 >> 32) & 0xffffu); hv[1] = (float)cv.f;
          cv.u = (unsigned short)(e1 & 0xffffu);         hv[2] = (float)cv.f;
          cv.u = (unsigned short)((e1 >> 32) & 0xffffu); hv[3] = (float)cv.f; }

        float partial[10];
#pragma unroll
        for (int o = 0; o < 10; ++o) {
            float4v w4 = *(const float4v*)(Wfc + (size_t)o * HH + (tid << 2));
            partial[o] = hv[0]*w4[0] + hv[1]*w4[1] + hv[2]*w4[2] + hv[3]*w4[3];
        }
        float* r = (float*)smem;   // [10][256]
#pragma unroll
        for (int o = 0; o < 10; ++o) r[o * 256 + tid] = partial[o];
        __syncthreads();
        for (int off = 128; off >= 1; off >>= 1) {
            if (tid < off) {
#pragma unroll
                for (int o = 0; o < 10; ++o)
                    r[o * 256 + tid] += r[o * 256 + tid + off];
            }
            __syncthreads();
        }
        if (tid < 10) out[b * 10 + tid] = r[tid * 256] + bfc[tid];
    }
}

extern "C" void kernel_launch(void* const* d_in, const int* in_sizes, int n_in,
                              void* d_out, int out_size, void* d_ws, size_t ws_size,
                              hipStream_t stream) {
    (void)in_sizes; (void)n_in; (void)out_size; (void)ws_size;
    const float* x   = (const float*)d_in[0];
    const float* Wx  = (const float*)d_in[1];
    const float* bx  = (const float*)d_in[2];
    const float* Wh  = (const float*)d_in[3];
    const float* bh  = (const float*)d_in[4];
    const float* Wfc = (const float*)d_in[5];
    const float* bfc = (const float*)d_in[6];
    float* out = (float*)d_out;

    char* ws = (char*)d_ws;
    _Float16* xf  = (_Float16*)(ws + XF_OFF);
    unsigned* hb0 = (unsigned*)(ws + HB0_OFF);
    unsigned* hb1 = (unsigned*)(ws + HB1_OFF);

    // reset BOTH packed h buffers every call (epochs must restart at 0;
    // harness replays without re-poisoning)
    hipMemsetAsync(ws + HB0_OFF, 0, 524288, stream);

    k_prep_x<<<512, 256, 0, stream>>>(x, xf);
    k_gru_persist<<<256, 256, 0, stream>>>(xf, Wx, bx, Wh, bh, Wfc, bfc,
                                           hb0, hb1, out);
}

// Round 15
// 1490.089 us; speedup vs baseline: 1.1695x; 1.0953x over previous
//
#include <hip/hip_runtime.h>

// GRU: B=64, T=512, IN=256, H=1024, OUT=10.
// r9 structure + WAVE-DECOUPLED staging: wave wv stages/polls/strips only
// its own k-slice (producers wv*8..wv*8+7), reads only LDS it wrote
// (XOR swizzle stays inside the 512B wave slice) -> the strip->MFMA
// __syncthreads is deleted; each wave starts MFMAs when ITS 8 producers
// land. red double-buffered (t&1) -> ONE block sync per step.
// Wire format unchanged (proven): u32 {epoch:16|fp16:16}, 8B pair
// publish / 8B poll loads (4B publishes corrupt: r6/r12/r13; sc0 hangs:
// r4/r10; agent sc1 is the only validated channel).

#define TT  512
#define BB  64
#define KIN 256
#define HH  1024

typedef _Float16 half8   __attribute__((ext_vector_type(8)));
typedef _Float16 half4v  __attribute__((ext_vector_type(4)));
typedef float    float4v __attribute__((ext_vector_type(4)));

// ---- workspace layout (bytes) ----
#define XF_OFF   0u           // fp16 x [T][B][K] = 16,777,216
#define HB0_OFF  16777216u    // u32 {tag|h} ping [B][H] = 262,144
#define HB1_OFF  17039360u    // u32 {tag|h} pong [B][H] = 262,144

// x[b][t][k] f32 -> xf[t][b][k] fp16
__global__ __launch_bounds__(256) void k_prep_x(const float* __restrict__ x,
                                                _Float16* __restrict__ xf) {
    const int t   = blockIdx.x;
    const int tid = threadIdx.x;
    const int k4  = (tid & 63) << 2;
    const int bw  = tid >> 6;
#pragma unroll
    for (int bi = 0; bi < 16; ++bi) {
        const int b = (bw << 4) + bi;
        float4v v = *(const float4v*)(x + ((size_t)b * TT + t) * KIN + k4);
        half4v h;
        h[0] = (_Float16)v[0]; h[1] = (_Float16)v[1];
        h[2] = (_Float16)v[2]; h[3] = (_Float16)v[3];
        *(half4v*)(xf + ((size_t)t * BB + b) * KIN + k4) = h;
    }
}

__device__ __forceinline__ unsigned long long ld_ag64(const void* p) {
    return __hip_atomic_load((const unsigned long long*)p, __ATOMIC_RELAXED,
                             __HIP_MEMORY_SCOPE_AGENT);
}
__device__ __forceinline__ void st_ag64(void* p, unsigned long long v) {
    __hip_atomic_store((unsigned long long*)p, v, __ATOMIC_RELAXED,
                       __HIP_MEMORY_SCOPE_AGENT);
}

__device__ __forceinline__ float sigm_fast(float z) {
    return __builtin_amdgcn_rcpf(1.f + __expf(-z));
}
__device__ __forceinline__ float tanh_fast(float z) {
    float e = __expf(-2.f * __builtin_fabsf(z));
    float r = (1.f - e) * __builtin_amdgcn_rcpf(1.f + e);
    return __builtin_copysignf(r, z);
}

__global__ __launch_bounds__(256, 1) void k_gru_persist(
    const _Float16* __restrict__ xf, const float* __restrict__ Wx,
    const float* __restrict__ bx, const float* __restrict__ Wh,
    const float* __restrict__ bh, const float* __restrict__ Wfc,
    const float* __restrict__ bfc, unsigned* __restrict__ hb0,
    unsigned* __restrict__ hb1, float* __restrict__ out)
{
    __shared__ char smem[57344];
    _Float16* h_lds = (_Float16*)smem;             // [8 b][1024 k] swz, 16KB
    float*    redm  = (float*)(smem + 16384);      // 2 x 5120 f32 (dbuf), 40KB

    const int tid  = threadIdx.x;
    const int lane = tid & 63;
    const int wv   = tid >> 6;          // wave = K-slice (256 k each)
    const int jsl  = blockIdx.x & 31;   // j-slice (32 of them)
    const int btl  = blockIdx.x >> 5;   // batch group (8 of them, 8 b each)
    const int j0   = jsl << 5;          // 32 j per block
    const int b0   = btl << 3;          // 8 b per block

    const int arow = lane & 15;         // MFMA A row (j) / B+D col (b)
    const int kg   = lane >> 4;         // MFMA k-group
    const int br8  = arow & 7;          // clamped b row (8 valid batches)
    const int swz  = br8 << 4;

    // ---- resident weights: single fp16 MFMA A-fragments, 2 j-tiles ----
    half8 ah[2][3][8], ax[2][3][2];
#pragma unroll
    for (int jt = 0; jt < 2; ++jt) {
#pragma unroll
        for (int g = 0; g < 3; ++g) {
            const int row = (g << 10) + j0 + (jt << 4) + arow;
#pragma unroll
            for (int s = 0; s < 8; ++s) {
                const float* p = Wh + (size_t)row * HH + (wv << 8) + (s << 5) + (kg << 3);
#pragma unroll
                for (int e = 0; e < 8; ++e) ah[jt][g][s][e] = (_Float16)p[e];
            }
#pragma unroll
            for (int s = 0; s < 2; ++s) {
                const float* p = Wx + (size_t)row * KIN + (wv << 6) + (s << 5) + (kg << 3);
#pragma unroll
                for (int e = 0; e < 8; ++e) ax[jt][g][s][e] = (_Float16)p[e];
            }
        }
    }

    const int jh  = tid & 31;       // owned j (consecutive tid -> consecutive j)
    const int bhi = tid >> 5;       // owned b (0..7)
    const int j   = j0 + jh;
    const int jt_f = jh >> 4, jrow_f = jh & 15;
    const float bxr = bx[j], bxi = bx[HH + j], bxn = bx[2 * HH + j];
    const float bhr = bh[j], bhii = bh[HH + j], bhn = bh[2 * HH + j];
    float hprev = 0.f;

    // ---- x B-fragments in registers ----
    const size_t xoff = (size_t)(b0 + br8) * KIN + (wv << 6) + (kg << 3);
    half8 xb0 = *(const half8*)(xf + xoff);
    half8 xb1 = *(const half8*)(xf + xoff + 32);

    for (int t = 0; t < TT; ++t) {
        const unsigned* hs = (t & 1) ? hb1 : hb0;
        unsigned*       hd = (t & 1) ? hb0 : hb1;

        // ---- (A) wave-local staging: wave wv stages its own k-slice ----
        // chunk i of lane: row = i>>1 (0..7), u64-chunk ch = wv*128 +
        // (i&1)*64 + lane  (within-row). 16 u64/lane, 1024 u64/wave.
        unsigned long long d[16];
#pragma unroll
        for (int i = 0; i < 16; ++i) {
            int row = i >> 1;
            int ch  = (wv << 7) + ((i & 1) << 6) + lane;
            d[i] = ld_ag64(hs + ((size_t)(b0 + row) << 10) + (ch << 1));
        }

        // ---- (B) x-MFMAs (no h dependency; overlap producer latency) ----
        float4v ar0 = {0,0,0,0}, ai0 = {0,0,0,0}, ax0 = {0,0,0,0}, ah0 = {0,0,0,0};
        float4v ar1 = {0,0,0,0}, ai1 = {0,0,0,0}, ax1 = {0,0,0,0}, ah1 = {0,0,0,0};
        ar0 = __builtin_amdgcn_mfma_f32_16x16x32_f16(ax[0][0][0], xb0, ar0, 0, 0, 0);
        ai0 = __builtin_amdgcn_mfma_f32_16x16x32_f16(ax[0][1][0], xb0, ai0, 0, 0, 0);
        ax0 = __builtin_amdgcn_mfma_f32_16x16x32_f16(ax[0][2][0], xb0, ax0, 0, 0, 0);
        ar1 = __builtin_amdgcn_mfma_f32_16x16x32_f16(ax[1][0][0], xb0, ar1, 0, 0, 0);
        ai1 = __builtin_amdgcn_mfma_f32_16x16x32_f16(ax[1][1][0], xb0, ai1, 0, 0, 0);
        ax1 = __builtin_amdgcn_mfma_f32_16x16x32_f16(ax[1][2][0], xb0, ax1, 0, 0, 0);
        ar0 = __builtin_amdgcn_mfma_f32_16x16x32_f16(ax[0][0][1], xb1, ar0, 0, 0, 0);
        ai0 = __builtin_amdgcn_mfma_f32_16x16x32_f16(ax[0][1][1], xb1, ai0, 0, 0, 0);
        ax0 = __builtin_amdgcn_mfma_f32_16x16x32_f16(ax[0][2][1], xb1, ax0, 0, 0, 0);
        ar1 = __builtin_amdgcn_mfma_f32_16x16x32_f16(ax[1][0][1], xb1, ar1, 0, 0, 0);
        ai1 = __builtin_amdgcn_mfma_f32_16x16x32_f16(ax[1][1][1], xb1, ai1, 0, 0, 0);
        ax1 = __builtin_amdgcn_mfma_f32_16x16x32_f16(ax[1][2][1], xb1, ax1, 0, 0, 0);

        // ---- (C) prefetch next-step x fragments ----
        const int tn = (t + 1 < TT) ? (t + 1) : t;
        const size_t xoffn = (size_t)tn * (BB * KIN) + xoff;
        half8 nb0 = *(const half8*)(xf + xoffn);
        half8 nb1 = *(const half8*)(xf + xoffn + 32);

        // ---- (D) pend-mask poll over the wave's own 8 producers ----
        {
            const unsigned tgt = (unsigned)t;
            unsigned pend = 0xffffu;
            for (;;) {
                unsigned np = 0;
#pragma unroll
                for (int i = 0; i < 16; ++i)
                    if ((pend >> i) & 1u)
                        if (((unsigned)(d[i] >> 16) & 0xffffu) < tgt) np |= (1u << i);
                if (np == 0) break;
                pend = np;
#pragma unroll
                for (int i = 0; i < 16; ++i)
                    if ((pend >> i) & 1u) {
                        int row = i >> 1;
                        int ch  = (wv << 7) + ((i & 1) << 6) + lane;
                        d[i] = ld_ag64(hs + ((size_t)(b0 + row) << 10) + (ch << 1));
                    }
            }
        }

        // ---- (E) strip tags -> swizzled LDS (wave-own slice; NO sync) ----
#pragma unroll
        for (int i = 0; i < 16; ++i) {
            int row = i >> 1;
            int ch  = (wv << 7) + ((i & 1) << 6) + lane;
            unsigned lo = (unsigned)d[i];
            unsigned hi = (unsigned)(d[i] >> 32);
            *(unsigned*)((char*)h_lds + (row << 11)
                + ((ch << 2) ^ (row << 4))) = (lo & 0xffffu) | (hi << 16);
        }
        // no __syncthreads: (F) reads only this wave's slice (swz toggles
        // bits 4-6, stays inside the 512B wave region); lgkmcnt orders it.

        // ---- (F) h-MFMAs: each bf feeds 6 MFMAs (3 gates x 2 j-tiles) ----
#pragma unroll
        for (int s = 0; s < 8; ++s) {
            half8 bf = *(const half8*)((char*)h_lds + (br8 << 11)
                        + (((wv << 9) + (s << 6) + (kg << 4)) ^ swz));
            ar0 = __builtin_amdgcn_mfma_f32_16x16x32_f16(ah[0][0][s], bf, ar0, 0, 0, 0);
            ai0 = __builtin_amdgcn_mfma_f32_16x16x32_f16(ah[0][1][s], bf, ai0, 0, 0, 0);
            ah0 = __builtin_amdgcn_mfma_f32_16x16x32_f16(ah[0][2][s], bf, ah0, 0, 0, 0);
            ar1 = __builtin_amdgcn_mfma_f32_16x16x32_f16(ah[1][0][s], bf, ar1, 0, 0, 0);
            ai1 = __builtin_amdgcn_mfma_f32_16x16x32_f16(ah[1][1][s], bf, ai1, 0, 0, 0);
            ah1 = __builtin_amdgcn_mfma_f32_16x16x32_f16(ah[1][2][s], bf, ah1, 0, 0, 0);
        }

        // ---- (G) reduction into double-buffered red; ONE sync per step ----
        float* redp = redm + (t & 1) * 5120;
        if (arow < 8) {
            int wb = ((wv << 3) + arow) * 20 + (kg << 2);
            *(float4v*)&redp[wb]              = ar0;
            *(float4v*)&redp[wb + 640]        = ai0;
            *(float4v*)&redp[wb + 1280]       = ax0;
            *(float4v*)&redp[wb + 1920]       = ah0;
            *(float4v*)&redp[wb + 2560]       = ar1;
            *(float4v*)&redp[wb + 2560+640]   = ai1;
            *(float4v*)&redp[wb + 2560+1280]  = ax1;
            *(float4v*)&redp[wb + 2560+1920]  = ah1;
        }
        __syncthreads();

        float sr = 0.f, si = 0.f, sx = 0.f, sh = 0.f;
        {
            const int base = jt_f * 2560 + jrow_f;
#pragma unroll
            for (int w2 = 0; w2 < 4; ++w2) {
                int rb = base + ((w2 << 3) + bhi) * 20;
                sr += redp[rb];
                si += redp[rb + 640];
                sx += redp[rb + 1280];
                sh += redp[rb + 1920];
            }
        }
        float rg = sigm_fast(sr + bxr + bhr);
        float ig = sigm_fast(si + bxi + bhii);
        float ng = tanh_fast(sx + bxn + rg * (sh + bhn));
        hprev = ng + ig * (hprev - ng);

        // ---- (H) publish {epoch|h} pair (jh, jh^1) as one 8B store ----
        unsigned short hb16;
        { union { _Float16 f; unsigned short u; } cv; cv.f = (_Float16)hprev; hb16 = cv.u; }
        unsigned myw = (((unsigned)(t + 1)) << 16) | (unsigned)hb16;
        unsigned other = (unsigned)__shfl_xor((int)myw, 1, 64);
        if ((jh & 1) == 0) {
            unsigned long long pv = (unsigned long long)myw
                                  | ((unsigned long long)other << 32);
            st_ag64(hd + ((size_t)(b0 + bhi) << 10) + j, pv);
        }

        xb0 = nb0; xb1 = nb1;
        // no barrier: epochs carry the synchronization
    }

    // ---- FC: blocks 0..63 compute out[b][:] from final h (hb0, epoch 512) ----
    if (blockIdx.x < 64) {
        __syncthreads();
        const int b = blockIdx.x;
        const unsigned ftgt = (unsigned)TT;
        unsigned long long e0, e1;
        do { e0 = ld_ag64(hb0 + ((size_t)b << 10) + (tid << 2)); }
        while (((unsigned)(e0 >> 16) & 0xffffu) < ftgt || (unsigned)(e0 >> 48) < ftgt);
        do { e1 = ld_ag64(hb0 + ((size_t)b << 10) + (tid << 2) + 2); }
        while (((unsigned)(e1 >> 16) & 0xffffu) < ftgt || (unsigned)(e1 >> 48) < ftgt);

        float hv[4];
        { union { unsigned short u; _Float16 f; } cv;
          cv.u = (unsigned short)(e0 & 0xffffu);         hv[0] = (float)cv.f;
          cv.u = (unsigned short)((e0 >> 32) & 0xffffu); hv[1] = (float)cv.f;
          cv.u = (unsigned short)(e1 & 0xffffu);         hv[2] = (float)cv.f;
          cv.u = (unsigned short)((e1 >> 32) & 0xffffu); hv[3] = (float)cv.f; }

        float partial[10];
#pragma unroll
        for (int o = 0; o < 10; ++o) {
            float4v w4 = *(const float4v*)(Wfc + (size_t)o * HH + (tid << 2));
            partial[o] = hv[0]*w4[0] + hv[1]*w4[1] + hv[2]*w4[2] + hv[3]*w4[3];
        }
        float* r = (float*)smem;   // [10][256]
#pragma unroll
        for (int o = 0; o < 10; ++o) r[o * 256 + tid] = partial[o];
        __syncthreads();
        for (int off = 128; off >= 1; off >>= 1) {
            if (tid < off) {
#pragma unroll
                for (int o = 0; o < 10; ++o)
                    r[o * 256 + tid] += r[o * 256 + tid + off];
            }
            __syncthreads();
        }
        if (tid < 10) out[b * 10 + tid] = r[tid * 256] + bfc[tid];
    }
}

extern "C" void kernel_launch(void* const* d_in, const int* in_sizes, int n_in,
                              void* d_out, int out_size, void* d_ws, size_t ws_size,
                              hipStream_t stream) {
    (void)in_sizes; (void)n_in; (void)out_size; (void)ws_size;
    const float* x   = (const float*)d_in[0];
    const float* Wx  = (const float*)d_in[1];
    const float* bx  = (const float*)d_in[2];
    const float* Wh  = (const float*)d_in[3];
    const float* bh  = (const float*)d_in[4];
    const float* Wfc = (const float*)d_in[5];
    const float* bfc = (const float*)d_in[6];
    float* out = (float*)d_out;

    char* ws = (char*)d_ws;
    _Float16* xf  = (_Float16*)(ws + XF_OFF);
    unsigned* hb0 = (unsigned*)(ws + HB0_OFF);
    unsigned* hb1 = (unsigned*)(ws + HB1_OFF);

    // reset BOTH packed h buffers every call (epochs must restart at 0;
    // harness replays without re-poisoning)
    hipMemsetAsync(ws + HB0_OFF, 0, 524288, stream);

    k_prep_x<<<512, 256, 0, stream>>>(x, xf);
    k_gru_persist<<<256, 256, 0, stream>>>(xf, Wx, bx, Wh, bh, Wfc, bfc,
                                           hb0, hb1, out);
}